// Round 1
// baseline (196.672 us; speedup 1.0000x reference)
//
#include <hip/hip_runtime.h>
#include <math.h>

// Problem dims (from reference): B=4, C=64, T=16, H=128, W=128, fp32.
#define BB 4
#define CC 64
#define TT 16
#define HH 128
#define WW 128
#define HALO 16           // max spatial dilation
#define PW (WW + 2*HALO)  // padded LDS row stride = 160 floats (160%32==0 -> uniform bank map)

__device__ __forceinline__ float softplus_f(float x) {
    // jax.nn.softplus = log1p(exp(x)); inputs are ~0.1 so no overflow guard needed,
    // but keep a cheap one for safety.
    return (x > 20.0f) ? x : log1pf(expf(x));
}

__global__ __launch_bounds__(256) void lap_st_kernel(
    const float* __restrict__ u,
    const float* __restrict__ Ds,   // (3, 64)
    const float* __restrict__ Dt,   // (2, 64)
    float* __restrict__ out)
{
    // 128 rows x 160 floats = 80 KB -> 2 blocks/CU on 160 KB LDS.
    __shared__ __align__(16) float sm[HH * PW];

    const int plane = blockIdx.x;          // ((b*C + c)*T + t)
    const int t  = plane & (TT - 1);
    const int bc = plane >> 4;             // b*C + c
    const int c  = bc & (CC - 1);

    const float cs0 = softplus_f(Ds[0 * CC + c]);
    const float cs1 = softplus_f(Ds[1 * CC + c]);
    const float cs2 = softplus_f(Ds[2 * CC + c]);
    const float ct0 = softplus_f(Dt[0 * CC + c]);
    const float ct1 = softplus_f(Dt[1 * CC + c]);
    // coefficient on the center value: -4*sum(cs) - sum(ct)
    const float cu = -4.0f * (cs0 + cs1 + cs2) - (ct0 + ct1);

    const size_t plane_off = (size_t)plane * (HH * WW);
    const float4* up4 = (const float4*)(u + plane_off);

    // ---- stage plane into LDS (interior region) ----
    for (int k = threadIdx.x; k < HH * WW / 4; k += 256) {
        float4 v = up4[k];
        int row = k >> 5;            // 32 float4-chunks per row
        int col = (k & 31) << 2;
        *(float4*)&sm[row * PW + HALO + col] = v;
    }
    __syncthreads();

    // ---- fill replicate column halos ----
    for (int idx = threadIdx.x; idx < HH * 2 * HALO; idx += 256) {
        int row = idx >> 5;          // 32 halo floats per row
        int j = idx & 31;
        if (j < HALO)
            sm[row * PW + j] = sm[row * PW + HALO];                       // left edge
        else
            sm[row * PW + HALO + WW + (j - HALO)] = sm[row * PW + HALO + WW - 1]; // right edge
    }
    __syncthreads();

    // temporal past planes (causal, edge-clamped)
    const int t1 = (t >= 1) ? t - 1 : 0;
    const int t2 = (t >= 2) ? t - 2 : 0;
    const float4* p1_4 = (const float4*)(u + ((size_t)(bc * TT + t1)) * (HH * WW));
    const float4* p2_4 = (const float4*)(u + ((size_t)(bc * TT + t2)) * (HH * WW));
    float4* out4 = (float4*)(out + plane_off);

    // ---- compute: each thread does 16 float4 chunks ----
    for (int k = threadIdx.x; k < HH * WW / 4; k += 256) {
        int row = k >> 5;
        int col = (k & 31) << 2;
        const float* rp = &sm[row * PW + HALO];

        // row-clamped neighbor rows (clamping a whole chunk keeps b128 alignment)
        int rU1  = (row >= 1)  ? row - 1  : 0;
        int rD1  = (row <= HH - 2)  ? row + 1  : HH - 1;
        int rU4  = (row >= 4)  ? row - 4  : 0;
        int rD4  = (row <= HH - 5)  ? row + 4  : HH - 1;
        int rU16 = (row >= 16) ? row - 16 : 0;
        int rD16 = (row <= HH - 17) ? row + 16 : HH - 1;

        float4 c0   = *(const float4*)&rp[col];
        float4 vu1  = *(const float4*)&sm[rU1  * PW + HALO + col];
        float4 vd1  = *(const float4*)&sm[rD1  * PW + HALO + col];
        float4 vu4  = *(const float4*)&sm[rU4  * PW + HALO + col];
        float4 vd4  = *(const float4*)&sm[rD4  * PW + HALO + col];
        float4 vu16 = *(const float4*)&sm[rU16 * PW + HALO + col];
        float4 vd16 = *(const float4*)&sm[rD16 * PW + HALO + col];
        float4 l4   = *(const float4*)&rp[col - 4];   // also provides d=1 left for elem 0
        float4 r4   = *(const float4*)&rp[col + 4];   // also provides d=1 right for elem 3
        float4 l16  = *(const float4*)&rp[col - 16];
        float4 r16  = *(const float4*)&rp[col + 16];

        float4 p1 = p1_4[k];
        float4 p2 = p2_4[k];

        float4 o;
        o.x = cs0 * (vu1.x + vd1.x + l4.w + c0.y)
            + cs1 * (vu4.x + vd4.x + l4.x + r4.x)
            + cs2 * (vu16.x + vd16.x + l16.x + r16.x)
            + cu * c0.x + ct0 * p1.x + ct1 * p2.x;
        o.y = cs0 * (vu1.y + vd1.y + c0.x + c0.z)
            + cs1 * (vu4.y + vd4.y + l4.y + r4.y)
            + cs2 * (vu16.y + vd16.y + l16.y + r16.y)
            + cu * c0.y + ct0 * p1.y + ct1 * p2.y;
        o.z = cs0 * (vu1.z + vd1.z + c0.y + c0.w)
            + cs1 * (vu4.z + vd4.z + l4.z + r4.z)
            + cs2 * (vu16.z + vd16.z + l16.z + r16.z)
            + cu * c0.z + ct0 * p1.z + ct1 * p2.z;
        o.w = cs0 * (vu1.w + vd1.w + c0.z + r4.x)
            + cs1 * (vu4.w + vd4.w + l4.w + r4.w)
            + cs2 * (vu16.w + vd16.w + l16.w + r16.w)
            + cu * c0.w + ct0 * p1.w + ct1 * p2.w;

        out4[k] = o;
    }
}

extern "C" void kernel_launch(void* const* d_in, const int* in_sizes, int n_in,
                              void* d_out, int out_size, void* d_ws, size_t ws_size,
                              hipStream_t stream) {
    const float* u  = (const float*)d_in[0];
    const float* Ds = (const float*)d_in[1];
    const float* Dt = (const float*)d_in[2];
    float* out = (float*)d_out;

    const int nplanes = BB * CC * TT;  // 4096
    lap_st_kernel<<<dim3(nplanes), dim3(256), 0, stream>>>(u, Ds, Dt, out);
}

// Round 2
// 128.980 us; speedup vs baseline: 1.5248x; 1.5248x over previous
//
#include <hip/hip_runtime.h>
#include <math.h>

// Problem dims (from reference): B=4, C=64, T=16, H=128, W=128, fp32.
#define BB 4
#define CC 64
#define TT 16
#define HH 128
#define WW 128
#define HALO 16           // max spatial dilation
#define PW (WW + 2*HALO)  // padded LDS row stride = 160 floats

__device__ __forceinline__ float softplus_f(float x) {
    return (x > 20.0f) ? x : log1pf(expf(x));
}

// One block per (b,c). Loops t=0..15; temporal history (t-1, t-2) kept in
// registers (4 float4 chunks/thread/plane), so temporal taps cost zero
// global traffic. Spatial taps via a full-plane LDS buffer with 16-col
// replicate halo (80 KB -> fits 1024-thread block at 16 waves/CU).
__global__ __launch_bounds__(1024, 4) void lap_st_kernel(
    const float* __restrict__ u,
    const float* __restrict__ Ds,   // (3, 64)
    const float* __restrict__ Dt,   // (2, 64)
    float* __restrict__ out)
{
    __shared__ __align__(16) float sm[HH * PW];

    const int bc = blockIdx.x;             // b*C + c, 0..255
    const int c  = bc & (CC - 1);
    const int tid = threadIdx.x;

    const float cs0 = softplus_f(Ds[0 * CC + c]);
    const float cs1 = softplus_f(Ds[1 * CC + c]);
    const float cs2 = softplus_f(Ds[2 * CC + c]);
    const float ct0 = softplus_f(Dt[0 * CC + c]);
    const float ct1 = softplus_f(Dt[1 * CC + c]);
    // center coefficient: -4*sum(cs) - sum(ct)
    const float cu = -4.0f * (cs0 + cs1 + cs2) - (ct0 + ct1);

    const size_t bc_off = (size_t)bc * TT * (HH * WW);

    float4 cur[4], pm1[4], pm2[4];

    for (int t = 0; t < TT; ++t) {
        const float4* up4  = (const float4*)(u   + bc_off + (size_t)t * (HH * WW));
        float4*       out4 = (float4*)      (out + bc_off + (size_t)t * (HH * WW));

        __syncthreads();   // previous iteration's compute done -> safe to overwrite sm

        // ---- stage plane t into LDS; halos written straight from registers ----
        #pragma unroll
        for (int i = 0; i < 4; ++i) {
            const int k = tid + (i << 10);       // chunk index 0..4095
            float4 v = up4[k];
            cur[i] = v;
            const int row  = k >> 5;             // 32 float4-chunks per row
            const int colc = k & 31;
            *(float4*)&sm[row * PW + HALO + (colc << 2)] = v;
            if (colc == 0) {                      // left replicate halo
                float4 s = make_float4(v.x, v.x, v.x, v.x);
                float* hp = &sm[row * PW];
                *(float4*)&hp[0] = s; *(float4*)&hp[4] = s;
                *(float4*)&hp[8] = s; *(float4*)&hp[12] = s;
            } else if (colc == 31) {              // right replicate halo
                float4 s = make_float4(v.w, v.w, v.w, v.w);
                float* hp = &sm[row * PW + HALO + WW];
                *(float4*)&hp[0] = s; *(float4*)&hp[4] = s;
                *(float4*)&hp[8] = s; *(float4*)&hp[12] = s;
            }
        }
        if (t == 0) {   // causal edge clamp: u[-1] = u[-2] = u[0] -> temporal term 0
            #pragma unroll
            for (int i = 0; i < 4; ++i) { pm1[i] = cur[i]; pm2[i] = cur[i]; }
        }
        __syncthreads();

        // ---- compute ----
        #pragma unroll
        for (int i = 0; i < 4; ++i) {
            const int k   = tid + (i << 10);
            const int row = k >> 5;
            const int col = (k & 31) << 2;
            const float* rp = &sm[row * PW + HALO];

            const int rU1  = (row >= 1)       ? row - 1  : 0;
            const int rD1  = (row <= HH - 2)  ? row + 1  : HH - 1;
            const int rU4  = (row >= 4)       ? row - 4  : 0;
            const int rD4  = (row <= HH - 5)  ? row + 4  : HH - 1;
            const int rU16 = (row >= 16)      ? row - 16 : 0;
            const int rD16 = (row <= HH - 17) ? row + 16 : HH - 1;

            const float4 c0   = cur[i];   // center comes from registers
            const float4 vu1  = *(const float4*)&sm[rU1  * PW + HALO + col];
            const float4 vd1  = *(const float4*)&sm[rD1  * PW + HALO + col];
            const float4 vu4  = *(const float4*)&sm[rU4  * PW + HALO + col];
            const float4 vd4  = *(const float4*)&sm[rD4  * PW + HALO + col];
            const float4 vu16 = *(const float4*)&sm[rU16 * PW + HALO + col];
            const float4 vd16 = *(const float4*)&sm[rD16 * PW + HALO + col];
            const float4 l4   = *(const float4*)&rp[col - 4];
            const float4 r4   = *(const float4*)&rp[col + 4];
            const float4 l16  = *(const float4*)&rp[col - 16];
            const float4 r16  = *(const float4*)&rp[col + 16];

            const float4 p1 = pm1[i];
            const float4 p2 = pm2[i];

            float4 o;
            o.x = cs0 * (vu1.x + vd1.x + l4.w + c0.y)
                + cs1 * (vu4.x + vd4.x + l4.x + r4.x)
                + cs2 * (vu16.x + vd16.x + l16.x + r16.x)
                + cu * c0.x + ct0 * p1.x + ct1 * p2.x;
            o.y = cs0 * (vu1.y + vd1.y + c0.x + c0.z)
                + cs1 * (vu4.y + vd4.y + l4.y + r4.y)
                + cs2 * (vu16.y + vd16.y + l16.y + r16.y)
                + cu * c0.y + ct0 * p1.y + ct1 * p2.y;
            o.z = cs0 * (vu1.z + vd1.z + c0.y + c0.w)
                + cs1 * (vu4.z + vd4.z + l4.z + r4.z)
                + cs2 * (vu16.z + vd16.z + l16.z + r16.z)
                + cu * c0.z + ct0 * p1.z + ct1 * p2.z;
            o.w = cs0 * (vu1.w + vd1.w + c0.z + r4.x)
                + cs1 * (vu4.w + vd4.w + l4.w + r4.w)
                + cs2 * (vu16.w + vd16.w + l16.w + r16.w)
                + cu * c0.w + ct0 * p1.w + ct1 * p2.w;

            out4[k] = o;
        }

        // rotate temporal history: t -> t+1
        #pragma unroll
        for (int i = 0; i < 4; ++i) { pm2[i] = pm1[i]; pm1[i] = cur[i]; }
    }
}

extern "C" void kernel_launch(void* const* d_in, const int* in_sizes, int n_in,
                              void* d_out, int out_size, void* d_ws, size_t ws_size,
                              hipStream_t stream) {
    const float* u  = (const float*)d_in[0];
    const float* Ds = (const float*)d_in[1];
    const float* Dt = (const float*)d_in[2];
    float* out = (float*)d_out;

    const int nblocks = BB * CC;   // 256 -> one block per CU
    lap_st_kernel<<<dim3(nblocks), dim3(1024), 0, stream>>>(u, Ds, Dt, out);
}